// Round 9
// baseline (568.262 us; speedup 1.0000x reference)
//
#include <hip/hip_runtime.h>
#include <math.h>

#define N_NODES 50000
#define N_EDGES 800000
#define D 128          // NODE_DIM
#define DE 10          // EDGE_DIM
#define TE 64          // edges per tile (CSR-consecutive)
#define N_TILES (N_EDGES / TE)       // 12500
#define SST 132        // u32 words per packed-sum row in LDS (128 + 4 pad)
#define ASTR 136       // bf16 per A row in node_gemm LDS
#define OST 520        // bf16 per out row in node_gemm LDS
#define WP2_ELEMS (4 * 32 * 64 * 8)  // 65536 bf16 (128x512 packed)
#define WEF_ELEMS (16 * 64 * 8)      // 8192 bf16 (32x256 packed, k<10 live)
#define SCAN_BLOCKS 196              // 196*256 = 50176 >= 50000
#define CSTRIDE 16     // ints per histogram bin: one 64B line per node
#define SCAT_BLOCKS 1563             // ceil(800000/512)
#define GEMM_BLOCKS 782              // ceil(50000/64)

typedef __bf16 bf16x8 __attribute__((ext_vector_type(8)));
typedef __bf16 bf16x4 __attribute__((ext_vector_type(4)));
typedef __bf16 bf16x2 __attribute__((ext_vector_type(2)));
typedef float  f32x4  __attribute__((ext_vector_type(4)));
typedef unsigned int u32x4 __attribute__((ext_vector_type(4)));

__device__ __forceinline__ float fast_sigmoid(float x) {
    float t = __builtin_amdgcn_exp2f(-1.44269504089f * x);
    return __builtin_amdgcn_rcpf(1.0f + t);
}
__device__ __forceinline__ float fast_softplus(float x) {
    float t = __builtin_amdgcn_exp2f(-1.44269504089f * fabsf(x));
    return fmaxf(x, 0.0f) + 0.69314718056f * __builtin_amdgcn_logf(1.0f + t);
}
// low/high bf16 of a packed u32 -> f32 (1 VALU each)
__device__ __forceinline__ float bflo(unsigned int u) {
    return __builtin_bit_cast(float, u << 16);
}
__device__ __forceinline__ float bfhi(unsigned int u) {
    return __builtin_bit_cast(float, u & 0xFFFF0000u);
}

// ---- prep: pack node-GEMM weights | pack ef weights | hist + rank capture ----
// [0,256) wp2; [256,288) wef; [288,3413) hist.
// rank = the atomicAdd return value (edge's arrival order within its node),
// persisted as uchar (max degree ~45 for Binomial(800K, 1/50K) -- safe).
__global__ __launch_bounds__(256) void prep(
    const float* __restrict__ gw, const float* __restrict__ cw,
    const int* __restrict__ ei,
    __bf16* __restrict__ wp2, __bf16* __restrict__ wef,
    int* __restrict__ counts, unsigned char* __restrict__ rank)
{
    int bx = blockIdx.x, t = threadIdx.x;
    if (bx < 256) {
        int idx = bx * 256 + t;               // < 65536
        int j    = idx & 7;
        int lane = (idx >> 3) & 63;
        int nb   = (idx >> 9) & 31;
        int kb   = idx >> 14;                 // 0..3
        int k    = kb * 32 + ((lane >> 4) << 3) + j;   // 0..127
        int jp   = nb * 16 + (lane & 15);
        float v;
        if      (jp < 128) v = gw[k * D + jp];
        else if (jp < 256) v = cw[k * D + (jp - 128)];
        else if (jp < 384) v = gw[(128 + k) * D + (jp - 256)];
        else               v = cw[(128 + k) * D + (jp - 384)];
        wp2[idx] = (__bf16)v;
    } else if (bx < 288) {
        int idx = (bx - 256) * 256 + t;       // < 8192
        int j    = idx & 7;
        int lane = (idx >> 3) & 63;
        int nb   = idx >> 9;                  // 0..15 (even=gate, odd=cand)
        int k    = ((lane >> 4) << 3) + j;    // 0..31
        int col  = (nb >> 1) * 16 + (lane & 15);
        const float* w = (nb & 1) ? cw : gw;
        wef[idx] = (__bf16)((k < 10) ? w[(256 + k) * D + col] : 0.0f);
    } else {
        int e = (bx - 288) * 256 + t;         // exact: 3125*256 = 800000
        int r = atomicAdd(&counts[ei[e] * CSTRIDE], 1);
        rank[e] = (unsigned char)r;
    }
}

__global__ __launch_bounds__(256) void scan_partials(
    const int* __restrict__ counts, int* __restrict__ bsum)
{
    __shared__ int ss[256];
    int t = threadIdx.x;
    int i = blockIdx.x * 256 + t;
    int c = (i < N_NODES) ? counts[i * CSTRIDE] : 0;
    ss[t] = c;
    __syncthreads();
    #pragma unroll
    for (int off = 1; off < 256; off <<= 1) {
        int v = (t >= off) ? ss[t - off] : 0;
        __syncthreads();
        ss[t] += v;
        __syncthreads();
    }
    if (t == 255) bsum[blockIdx.x] = ss[255];
}

// Exclusive prefix split into {per-scanblock anchor (u32), local prefix (u16)}.
// Local prefix < block edge-sum (~4100 avg, <<65536) -- exact by construction.
// Everything lives OUTSIDE the U region so the fused gemm can overwrite
// counts/pbI without racing the scatter. counts dead after this kernel.
__global__ __launch_bounds__(256) void scan_final(
    const int* __restrict__ counts, const int* __restrict__ bsum,
    int* __restrict__ anchors, unsigned short* __restrict__ excl16)
{
    __shared__ int sb[256];
    __shared__ int ss[256];
    int t = threadIdx.x;
    sb[t] = (t < SCAN_BLOCKS) ? bsum[t] : 0;
    int i = blockIdx.x * 256 + t;
    int c = (i < N_NODES) ? counts[i * CSTRIDE] : 0;
    ss[t] = c;
    __syncthreads();
    #pragma unroll
    for (int off = 1; off < 256; off <<= 1) {
        int v  = (t >= off) ? ss[t - off] : 0;
        int vb = (t >= off) ? sb[t - off] : 0;
        __syncthreads();
        ss[t] += v;
        sb[t] += vb;
        __syncthreads();
    }
    if (t == 0) anchors[blockIdx.x] = blockIdx.x ? sb[blockIdx.x - 1] : 0;
    if (i < N_NODES) excl16[i] = (unsigned short)(ss[t] - c);
}

// ---- fused launch: ATOMIC-FREE pre-gathering scatter (blocks [0,1563))
// concurrent with the node projection GEMM (blocks [1563,2345)).
// pos = anchor + local-prefix + rank (unique, no atomics).
// Payload split: sdx = src|dst<<16 (u32), eid as u16+u8 (e < 2^20) -- keeps
// the workspace at 57.85 MB while giving edge_fuse fully coalesced headers.
// Safe: scatter reads {ei, rank, anchors, excl16} and writes {sdx, eidlo,
// eidhi}; gemm writes pbI over DEAD counts + paI in d_out. No overlap. ----
__global__ __launch_bounds__(512, 4) void scatter_gemm(
    const int* __restrict__ ei, const unsigned char* __restrict__ rank,
    const int* __restrict__ anchors, const unsigned short* __restrict__ excl16,
    unsigned int* __restrict__ sdx, unsigned short* __restrict__ eidlo,
    unsigned char* __restrict__ eidhi,
    const float* __restrict__ h, const __bf16* __restrict__ wp2,
    unsigned int* __restrict__ paI, unsigned int* __restrict__ pbI)
{
    if (blockIdx.x < SCAT_BLOCKS) {
        int e = blockIdx.x * 512 + threadIdx.x;
        if (e < N_EDGES) {
            int node = ei[e];
            int pos = anchors[node >> 8] + (int)excl16[node] + (int)rank[e];
            sdx[pos]   = (unsigned int)node | ((unsigned int)ei[N_EDGES + e] << 16);
            eidlo[pos] = (unsigned short)e;
            eidhi[pos] = (unsigned char)(e >> 16);
        }
        return;
    }

    // ---- node projection GEMM: [50048x128] @ [128x512] ----
    // Output INTERLEAVED: paI[n][c] = u32(bf16 gate_top_c, bf16 cand_top_c),
    // pbI[n][c] likewise for the mid (dst-side) halves.
    __shared__ __align__(16) __bf16 sm[64 * OST];   // 66,560 B; A-tile aliases base
    __bf16* za = sm;                                 // [64][ASTR] in phase A
    const int t  = threadIdx.x;
    const int r0 = (blockIdx.x - SCAT_BLOCKS) * 64;

    #pragma unroll
    for (int it = 0; it < 4; ++it) {
        int ch  = it * 512 + t;            // 2048 float4 chunks (64 rows x 32)
        int row = ch >> 5, cs = ch & 31;
        int node = r0 + row;
        float4 v = (node < N_NODES) ? *(const float4*)&h[(size_t)node * D + cs * 4]
                                    : make_float4(0.f, 0.f, 0.f, 0.f);
        bf16x4 o = { (__bf16)v.x, (__bf16)v.y, (__bf16)v.z, (__bf16)v.w };
        *(bf16x4*)&za[row * ASTR + cs * 4] = o;
    }
    __syncthreads();

    const int w = t >> 6, l = t & 63, quad = l >> 4, col16 = l & 15;
    f32x4 acc[4][4];
    #pragma unroll
    for (int mt = 0; mt < 4; ++mt)
        #pragma unroll
        for (int nt = 0; nt < 4; ++nt)
            acc[mt][nt] = (f32x4)0.0f;

    const __bf16* zp = &za[col16 * ASTR + quad * 8];
    const __bf16* bp = &wp2[(size_t)((w * 4) * 64 + l) * 8];

    #pragma unroll
    for (int kb = 0; kb < 4; ++kb) {
        bf16x8 afr[4];
        #pragma unroll
        for (int mt = 0; mt < 4; ++mt)
            afr[mt] = *(const bf16x8*)&zp[mt * 16 * ASTR + kb * 32];
        bf16x8 bfr[4];
        #pragma unroll
        for (int nt = 0; nt < 4; ++nt)
            bfr[nt] = *(const bf16x8*)&bp[(size_t)(kb * 32 + nt) * 512];
        #pragma unroll
        for (int mt = 0; mt < 4; ++mt)
            #pragma unroll
            for (int nt = 0; nt < 4; ++nt)
                acc[mt][nt] = __builtin_amdgcn_mfma_f32_16x16x32_bf16(
                    afr[mt], bfr[nt], acc[mt][nt], 0, 0, 0);
    }
    __syncthreads();   // A dead; reuse sm as out-tile

    #pragma unroll
    for (int mt = 0; mt < 4; ++mt)
        #pragma unroll
        for (int nt = 0; nt < 4; ++nt)
            #pragma unroll
            for (int r = 0; r < 4; ++r) {
                int row  = mt * 16 + quad * 4 + r;
                int colj = (w * 4 + nt) * 16 + col16;
                sm[row * OST + colj] = (__bf16)acc[mt][nt][r];
            }
    __syncthreads();

    // epilogue: interleave (gate, cand) pairs and store 16B chunks
    #pragma unroll
    for (int it = 0; it < 8; ++it) {
        int ch   = it * 512 + t;           // 4096 chunks of 4 u32 (16B)
        int row  = ch >> 6;
        int sub  = ch & 63;
        int hp   = sub >> 5;               // 0 = paI (top), 1 = pbI (mid)
        int c0   = (sub & 31) * 4;
        int node = r0 + row;
        if (node < N_NODES) {
            const __bf16* sr = &sm[row * OST + hp * 256];
            bf16x4 gl = *(const bf16x4*)&sr[c0];
            bf16x4 cl = *(const bf16x4*)&sr[128 + c0];
            unsigned int wds[4];
            #pragma unroll
            for (int i = 0; i < 4; ++i) {
                bf16x2 pr = { gl[i], cl[i] };
                wds[i] = __builtin_bit_cast(unsigned int, pr);
            }
            unsigned int* dp = hp ? pbI : paI;
            *(uint4*)&dp[(size_t)node * 128 + c0] = *(const uint4*)&wds[0];
        }
    }
}

// ---- edge kernel: coalesced pre-gathered header + staged-LDS packed sums
// (16B loads, the R2-proven width) + tiny ef-MFMA with BIAS folded into the
// C operand + fused activation/in-register segmented reduction.
// The ms roundtrip, the 16-iter serial loop, and the final barrier from the
// R2 structure are deleted: each thread's C-fragment holds 4 CONSECUTIVE
// CSR edges per mt (e = mt*16 + quad*4 + r), so run-segmentation happens in
// registers; ~1.25 coalesced atomics per 4-edge window. ----
__global__ __launch_bounds__(512, 6) void edge_fuse(
    const unsigned int* __restrict__ paI, const unsigned int* __restrict__ pbI,
    const unsigned int* __restrict__ sdx, const unsigned short* __restrict__ eidlo,
    const unsigned char* __restrict__ eidhi,
    const float* __restrict__ ef, const __bf16* __restrict__ wef,
    const float* __restrict__ gb, const float* __restrict__ cb,
    float* __restrict__ agg)
{
    __shared__ __align__(16) unsigned int sbuf[TE * SST];  // 33,792 B packed sums
    __shared__ __align__(16) __bf16 zE[TE * 32];           // 4 KB
    __shared__ int s_src[TE], s_dst[TE];

    const int t  = threadIdx.x;
    const int e0 = blockIdx.x * TE;
    const int w = t >> 6, l = t & 63, quad = l >> 4, col16 = l & 15;

    // early independent loads (in flight across the header)
    const __bf16* wpp = &wef[(size_t)((w * 2) * 64 + l) * 8];
    bf16x8 bfr0 = *(const bf16x8*)&wpp[0];
    bf16x8 bfr1 = *(const bf16x8*)&wpp[512];
    const int c = w * 16 + col16;
    const float gbv = gb[c], cbv = cb[c];

    if (t < TE) {
        unsigned int sd = sdx[e0 + t];     // coalesced 4B
        int eid = (int)eidlo[e0 + t] | ((int)eidhi[e0 + t] << 16);
        s_src[t] = (int)(sd & 0xFFFFu);
        s_dst[t] = (int)(sd >> 16);
        // ef row -> zE (k 0..9 live, 10..31 zero)
        const float* efr = &ef[(size_t)eid * DE];
        __bf16* row = &zE[t * 32];
        #pragma unroll
        for (int j = 0; j < 5; ++j) {
            float2 a = *(const float2*)&efr[j * 2];
            bf16x2 pr = { (__bf16)a.x, (__bf16)a.y };
            *(bf16x2*)&row[j * 2] = pr;
        }
        *(bf16x2*)&row[10] = (bf16x2)(__bf16)0.0f;
        *(bf16x4*)&row[12] = (bf16x4)(__bf16)0.0f;
        *(bf16x8*)&row[16] = (bf16x8)(__bf16)0.0f;
        *(bf16x8*)&row[24] = (bf16x8)(__bf16)0.0f;
    }
    __syncthreads();

    // staged packed sums: 1024 tasks = 64 edges x 16 col-groups of 8.
    // 16B loads from interleaved proj (512B contiguous per edge -> coalesced).
    #pragma unroll
    for (int it = 0; it < 2; ++it) {
        int id  = it * 512 + t;
        int e   = id >> 4, grp = id & 15;
        int src = s_src[e], dst = s_dst[e];
        int c0  = grp * 8;
        u32x4 a0 = *(const u32x4*)&paI[(size_t)src * 128 + c0];
        u32x4 a1 = *(const u32x4*)&paI[(size_t)src * 128 + c0 + 4];
        u32x4 b0 = *(const u32x4*)&pbI[(size_t)dst * 128 + c0];
        u32x4 b1 = *(const u32x4*)&pbI[(size_t)dst * 128 + c0 + 4];
        unsigned int o[8];
        #pragma unroll
        for (int j = 0; j < 4; ++j) {
            bf16x2 p0 = { (__bf16)(bflo(a0[j]) + bflo(b0[j])),
                          (__bf16)(bfhi(a0[j]) + bfhi(b0[j])) };
            bf16x2 p1 = { (__bf16)(bflo(a1[j]) + bflo(b1[j])),
                          (__bf16)(bfhi(a1[j]) + bfhi(b1[j])) };
            o[j]     = __builtin_bit_cast(unsigned int, p0);
            o[j + 4] = __builtin_bit_cast(unsigned int, p1);
        }
        *(uint4*)&sbuf[e * SST + c0]     = *(const uint4*)&o[0];
        *(uint4*)&sbuf[e * SST + c0 + 4] = *(const uint4*)&o[4];
    }
    __syncthreads();

    // ef @ W_ef with bias as the MFMA C operand (saves the adds later)
    const f32x4 bg4 = { gbv, gbv, gbv, gbv };
    const f32x4 bc4 = { cbv, cbv, cbv, cbv };
    f32x4 accg[4], accc[4];
    #pragma unroll
    for (int mt = 0; mt < 4; ++mt) {
        const bf16x8 a = *(const bf16x8*)&zE[(mt * 16 + col16) * 32 + quad * 8];
        accg[mt] = __builtin_amdgcn_mfma_f32_16x16x32_bf16(a, bfr0, bg4, 0, 0, 0);
        accc[mt] = __builtin_amdgcn_mfma_f32_16x16x32_bf16(a, bfr1, bc4, 0, 0, 0);
    }

    // fused activation + in-register segmented reduce over 4-edge windows
    #pragma unroll
    for (int mt = 0; mt < 4; ++mt) {
        const int eb = mt * 16 + quad * 4;
        float m[4]; int nd[4];
        #pragma unroll
        for (int r = 0; r < 4; ++r) {
            unsigned int u = sbuf[(eb + r) * SST + c];
            float g = bflo(u) + accg[mt][r];
            float x = bfhi(u) + accc[mt][r];
            m[r]  = fast_sigmoid(g) * fast_softplus(x);
            nd[r] = s_src[eb + r];
        }
        float s = m[0];
        #pragma unroll
        for (int r = 1; r < 4; ++r) {
            if (nd[r] != nd[r - 1]) {
                atomicAdd(&agg[(size_t)nd[r - 1] * D + c], s);
                s = 0.0f;
            }
            s += m[r];
        }
        atomicAdd(&agg[(size_t)nd[3] * D + c], s);
    }
}

__global__ __launch_bounds__(256) void col_stats(
    const float* __restrict__ agg, float* __restrict__ stats)
{
    const int t    = threadIdx.x;
    const int col  = t & 127;
    const int half = t >> 7;
    float s = 0.0f, s2 = 0.0f;
    for (int r = blockIdx.x * 2 + half; r < N_NODES; r += gridDim.x * 2) {
        float v = agg[(size_t)r * D + col];
        s += v; s2 += v * v;
    }
    atomicAdd(&stats[col], s);
    atomicAdd(&stats[128 + col], s2);
}

__global__ __launch_bounds__(256) void out_softplus(
    const float* __restrict__ h, const float* __restrict__ agg,
    const float* __restrict__ stats, const float* __restrict__ gamma,
    const float* __restrict__ beta, float* __restrict__ out)
{
    __shared__ float sc[128], bi[128];
    int t = threadIdx.x;
    if (t < 128) {
        const float inv_n = 1.0f / (float)N_NODES;
        float mean = stats[t] * inv_n;
        float var  = stats[128 + t] * inv_n - mean * mean;
        var = fmaxf(var, 0.0f);
        float rstd = rsqrtf(var + 1e-5f);
        float s = rstd * gamma[t];
        sc[t] = s;
        bi[t] = beta[t] - mean * s;
    }
    __syncthreads();
    int idx4 = blockIdx.x * 256 + t;
    int base = idx4 * 4;
    if (base < N_NODES * D) {
        float4 hv = *(const float4*)&h[base];
        float4 av = *(const float4*)&agg[base];
        int c = base & 127;
        float4 o;
        o.x = fast_softplus(hv.x + av.x * sc[c + 0] + bi[c + 0]);
        o.y = fast_softplus(hv.y + av.y * sc[c + 1] + bi[c + 1]);
        o.z = fast_softplus(hv.z + av.z * sc[c + 2] + bi[c + 2]);
        o.w = fast_softplus(hv.w + av.w * sc[c + 3] + bi[c + 3]);
        *(float4*)&out[base] = o;
    }
}

extern "C" void kernel_launch(void* const* d_in, const int* in_sizes, int n_in,
                              void* d_out, int out_size, void* d_ws, size_t ws_size,
                              hipStream_t stream) {
    const float* h     = (const float*)d_in[0];
    const int*   ei    = (const int*)  d_in[1];
    const float* ef    = (const float*)d_in[2];
    const float* gw    = (const float*)d_in[3];
    const float* gb    = (const float*)d_in[4];
    const float* cw    = (const float*)d_in[5];
    const float* cb    = (const float*)d_in[6];
    const float* gamma = (const float*)d_in[7];
    const float* beta  = (const float*)d_in[8];
    float* out = (float*)d_out;

    // Layout: [agg 25.6M][stats 1K][U: counts 3.2M -> pbI 25.6M][wp2 128K]
    //         [wef 16K][bsum 1K][anchors 1K][excl16 100K][rank 800K]
    //         [sdx 3.2M][eidlo 1.6M][eidhi 800K]  ~= 57.85 MB (< 58.6 proven)
    float*          agg     = (float*)d_ws;
    float*          stats   = agg + (size_t)N_NODES * D;
    int*            counts  = (int*)(stats + 256);           // U base (strided hist)
    unsigned int*   pbI     = (unsigned int*)counts;         // aliases U after scan_final
    char*           afterU  = (char*)counts + (size_t)N_NODES * 128 * sizeof(unsigned int);
    __bf16*         wp2     = (__bf16*)afterU;               // 131,072 B
    __bf16*         wef     = wp2 + WP2_ELEMS;               // 16,384 B
    int*            bsum    = (int*)(wef + WEF_ELEMS);       // 1 KB
    int*            anchors = bsum + 256;                    // 1 KB (196 used)
    unsigned short* excl16  = (unsigned short*)(anchors + 256);   // 100 KB
    unsigned char*  rank    = (unsigned char*)(excl16 + N_NODES); // 800 KB
    unsigned int*   sdx     = (unsigned int*)(rank + N_EDGES);    // 3.2 MB (4B-aligned)
    unsigned short* eidlo   = (unsigned short*)(sdx + N_EDGES);   // 1.6 MB
    unsigned char*  eidhi   = (unsigned char*)(eidlo + N_EDGES);  // 800 KB
    unsigned int*   paI     = (unsigned int*)d_out;          // 25.6 MB scratch until out

    // zero agg | stats | counts (one contiguous region) — R6-proven arrangement
    const size_t zero_bytes = ((size_t)N_NODES * D + 256) * sizeof(float)
                            + (size_t)N_NODES * CSTRIDE * sizeof(int);
    hipMemsetAsync(d_ws, 0, zero_bytes, stream);
    prep<<<3413, 256, 0, stream>>>(gw, cw, ei, wp2, wef, counts, rank);
    scan_partials<<<SCAN_BLOCKS, 256, 0, stream>>>(counts, bsum);
    scan_final<<<SCAN_BLOCKS, 256, 0, stream>>>(counts, bsum, anchors, excl16);
    scatter_gemm<<<SCAT_BLOCKS + GEMM_BLOCKS, 512, 0, stream>>>(
        ei, rank, anchors, excl16, sdx, eidlo, eidhi, h, wp2, paI, pbI);
    edge_fuse<<<N_TILES, 512, 0, stream>>>(
        paI, pbI, sdx, eidlo, eidhi, ef, wef, gb, cb, agg);
    col_stats<<<784, 256, 0, stream>>>(agg, stats);
    out_softplus<<<N_NODES * D / 4 / 256, 256, 0, stream>>>(
        h, agg, stats, gamma, beta, out);
}

// Round 10
// 341.037 us; speedup vs baseline: 1.6663x; 1.6663x over previous
//
#include <hip/hip_runtime.h>
#include <math.h>

#define N_NODES 50000
#define N_EDGES 800000
#define D 128          // NODE_DIM
#define DE 10          // EDGE_DIM
#define TE 64          // edges per tile (CSR-consecutive)
#define N_TILES (N_EDGES / TE)       // 12500
#define SST 132        // u32 words per packed-sum/m row in LDS (128 + 4 pad)
#define ASTR 136       // bf16 per A row in node_gemm LDS
#define OST 520        // bf16 per out row in node_gemm LDS
#define WP2_ELEMS (4 * 32 * 64 * 8)  // 65536 bf16 (128x512 packed)
#define WEF_ELEMS (16 * 64 * 8)      // 8192 bf16 (32x256 packed, k<10 live)
#define SCAN_BLOCKS 196              // 196*256 = 50176 >= 50000
#define CSTRIDE 16     // ints per histogram bin: one 64B line per node
#define SCAT_BLOCKS 1563             // ceil(800000/512)
#define GEMM_BLOCKS 782              // ceil(50000/64)

typedef __bf16 bf16x8 __attribute__((ext_vector_type(8)));
typedef __bf16 bf16x4 __attribute__((ext_vector_type(4)));
typedef __bf16 bf16x2 __attribute__((ext_vector_type(2)));
typedef float  f32x4  __attribute__((ext_vector_type(4)));
typedef unsigned int u32x4 __attribute__((ext_vector_type(4)));

__device__ __forceinline__ float fast_sigmoid(float x) {
    float t = __builtin_amdgcn_exp2f(-1.44269504089f * x);
    return __builtin_amdgcn_rcpf(1.0f + t);
}
__device__ __forceinline__ float fast_softplus(float x) {
    float t = __builtin_amdgcn_exp2f(-1.44269504089f * fabsf(x));
    return fmaxf(x, 0.0f) + 0.69314718056f * __builtin_amdgcn_logf(1.0f + t);
}
// low/high bf16 of a packed u32 -> f32 (1 VALU each)
__device__ __forceinline__ float bflo(unsigned int u) {
    return __builtin_bit_cast(float, u << 16);
}
__device__ __forceinline__ float bfhi(unsigned int u) {
    return __builtin_bit_cast(float, u & 0xFFFF0000u);
}

// ---- prep: pack node-GEMM weights | pack ef weights | hist + rank capture ----
// [0,256) wp2; [256,288) wef; [288,3413) hist.
// rank = the atomicAdd return value (edge's arrival order within its node),
// persisted as uchar (max degree ~45 for Binomial(800K, 1/50K) -- safe).
__global__ __launch_bounds__(256) void prep(
    const float* __restrict__ gw, const float* __restrict__ cw,
    const int* __restrict__ ei,
    __bf16* __restrict__ wp2, __bf16* __restrict__ wef,
    int* __restrict__ counts, unsigned char* __restrict__ rank)
{
    int bx = blockIdx.x, t = threadIdx.x;
    if (bx < 256) {
        int idx = bx * 256 + t;               // < 65536
        int j    = idx & 7;
        int lane = (idx >> 3) & 63;
        int nb   = (idx >> 9) & 31;
        int kb   = idx >> 14;                 // 0..3
        int k    = kb * 32 + ((lane >> 4) << 3) + j;   // 0..127
        int jp   = nb * 16 + (lane & 15);
        float v;
        if      (jp < 128) v = gw[k * D + jp];
        else if (jp < 256) v = cw[k * D + (jp - 128)];
        else if (jp < 384) v = gw[(128 + k) * D + (jp - 256)];
        else               v = cw[(128 + k) * D + (jp - 384)];
        wp2[idx] = (__bf16)v;
    } else if (bx < 288) {
        int idx = (bx - 256) * 256 + t;       // < 8192
        int j    = idx & 7;
        int lane = (idx >> 3) & 63;
        int nb   = idx >> 9;                  // 0..15 (even=gate, odd=cand)
        int k    = ((lane >> 4) << 3) + j;    // 0..31
        int col  = (nb >> 1) * 16 + (lane & 15);
        const float* w = (nb & 1) ? cw : gw;
        wef[idx] = (__bf16)((k < 10) ? w[(256 + k) * D + col] : 0.0f);
    } else {
        int e = (bx - 288) * 256 + t;         // exact: 3125*256 = 800000
        int r = atomicAdd(&counts[ei[e] * CSTRIDE], 1);
        rank[e] = (unsigned char)r;
    }
}

__global__ __launch_bounds__(256) void scan_partials(
    const int* __restrict__ counts, int* __restrict__ bsum)
{
    __shared__ int ss[256];
    int t = threadIdx.x;
    int i = blockIdx.x * 256 + t;
    int c = (i < N_NODES) ? counts[i * CSTRIDE] : 0;
    ss[t] = c;
    __syncthreads();
    #pragma unroll
    for (int off = 1; off < 256; off <<= 1) {
        int v = (t >= off) ? ss[t - off] : 0;
        __syncthreads();
        ss[t] += v;
        __syncthreads();
    }
    if (t == 255) bsum[blockIdx.x] = ss[255];
}

// Exclusive prefix split into {per-scanblock anchor (u32), local prefix (u16)}.
// Local prefix < block edge-sum (~4100 avg, <<65536) -- exact by construction.
// Everything lives OUTSIDE the U region so the fused gemm can overwrite
// counts/pbI without racing the scatter. counts dead after this kernel.
__global__ __launch_bounds__(256) void scan_final(
    const int* __restrict__ counts, const int* __restrict__ bsum,
    int* __restrict__ anchors, unsigned short* __restrict__ excl16)
{
    __shared__ int sb[256];
    __shared__ int ss[256];
    int t = threadIdx.x;
    sb[t] = (t < SCAN_BLOCKS) ? bsum[t] : 0;
    int i = blockIdx.x * 256 + t;
    int c = (i < N_NODES) ? counts[i * CSTRIDE] : 0;
    ss[t] = c;
    __syncthreads();
    #pragma unroll
    for (int off = 1; off < 256; off <<= 1) {
        int v  = (t >= off) ? ss[t - off] : 0;
        int vb = (t >= off) ? sb[t - off] : 0;
        __syncthreads();
        ss[t] += v;
        sb[t] += vb;
        __syncthreads();
    }
    if (t == 0) anchors[blockIdx.x] = blockIdx.x ? sb[blockIdx.x - 1] : 0;
    if (i < N_NODES) excl16[i] = (unsigned short)(ss[t] - c);
}

// ---- fused launch: ATOMIC-FREE pre-gathering scatter (blocks [0,1563))
// concurrent with the node projection GEMM (blocks [1563,2345)).
// pos = anchor + local-prefix + rank (unique, no atomics). ----
__global__ __launch_bounds__(512, 4) void scatter_gemm(
    const int* __restrict__ ei, const unsigned char* __restrict__ rank,
    const int* __restrict__ anchors, const unsigned short* __restrict__ excl16,
    unsigned int* __restrict__ sdx, unsigned short* __restrict__ eidlo,
    unsigned char* __restrict__ eidhi,
    const float* __restrict__ h, const __bf16* __restrict__ wp2,
    unsigned int* __restrict__ paI, unsigned int* __restrict__ pbI)
{
    if (blockIdx.x < SCAT_BLOCKS) {
        int e = blockIdx.x * 512 + threadIdx.x;
        if (e < N_EDGES) {
            int node = ei[e];
            int pos = anchors[node >> 8] + (int)excl16[node] + (int)rank[e];
            sdx[pos]   = (unsigned int)node | ((unsigned int)ei[N_EDGES + e] << 16);
            eidlo[pos] = (unsigned short)e;
            eidhi[pos] = (unsigned char)(e >> 16);
        }
        return;
    }

    // ---- node projection GEMM: [50048x128] @ [128x512] ----
    // Output INTERLEAVED: paI[n][c] = u32(bf16 gate_top_c, bf16 cand_top_c),
    // pbI[n][c] likewise for the mid (dst-side) halves.
    __shared__ __align__(16) __bf16 sm[64 * OST];   // 66,560 B; A-tile aliases base
    __bf16* za = sm;                                 // [64][ASTR] in phase A
    const int t  = threadIdx.x;
    const int r0 = (blockIdx.x - SCAT_BLOCKS) * 64;

    #pragma unroll
    for (int it = 0; it < 4; ++it) {
        int ch  = it * 512 + t;            // 2048 float4 chunks (64 rows x 32)
        int row = ch >> 5, cs = ch & 31;
        int node = r0 + row;
        float4 v = (node < N_NODES) ? *(const float4*)&h[(size_t)node * D + cs * 4]
                                    : make_float4(0.f, 0.f, 0.f, 0.f);
        bf16x4 o = { (__bf16)v.x, (__bf16)v.y, (__bf16)v.z, (__bf16)v.w };
        *(bf16x4*)&za[row * ASTR + cs * 4] = o;
    }
    __syncthreads();

    const int w = t >> 6, l = t & 63, quad = l >> 4, col16 = l & 15;
    f32x4 acc[4][4];
    #pragma unroll
    for (int mt = 0; mt < 4; ++mt)
        #pragma unroll
        for (int nt = 0; nt < 4; ++nt)
            acc[mt][nt] = (f32x4)0.0f;

    const __bf16* zp = &za[col16 * ASTR + quad * 8];
    const __bf16* bp = &wp2[(size_t)((w * 4) * 64 + l) * 8];

    #pragma unroll
    for (int kb = 0; kb < 4; ++kb) {
        bf16x8 afr[4];
        #pragma unroll
        for (int mt = 0; mt < 4; ++mt)
            afr[mt] = *(const bf16x8*)&zp[mt * 16 * ASTR + kb * 32];
        bf16x8 bfr[4];
        #pragma unroll
        for (int nt = 0; nt < 4; ++nt)
            bfr[nt] = *(const bf16x8*)&bp[(size_t)(kb * 32 + nt) * 512];
        #pragma unroll
        for (int mt = 0; mt < 4; ++mt)
            #pragma unroll
            for (int nt = 0; nt < 4; ++nt)
                acc[mt][nt] = __builtin_amdgcn_mfma_f32_16x16x32_bf16(
                    afr[mt], bfr[nt], acc[mt][nt], 0, 0, 0);
    }
    __syncthreads();   // A dead; reuse sm as out-tile

    #pragma unroll
    for (int mt = 0; mt < 4; ++mt)
        #pragma unroll
        for (int nt = 0; nt < 4; ++nt)
            #pragma unroll
            for (int r = 0; r < 4; ++r) {
                int row  = mt * 16 + quad * 4 + r;
                int colj = (w * 4 + nt) * 16 + col16;
                sm[row * OST + colj] = (__bf16)acc[mt][nt][r];
            }
    __syncthreads();

    // epilogue: interleave (gate, cand) pairs and store 16B chunks
    #pragma unroll
    for (int it = 0; it < 8; ++it) {
        int ch   = it * 512 + t;           // 4096 chunks of 4 u32 (16B)
        int row  = ch >> 6;
        int sub  = ch & 63;
        int hp   = sub >> 5;               // 0 = paI (top), 1 = pbI (mid)
        int c0   = (sub & 31) * 4;
        int node = r0 + row;
        if (node < N_NODES) {
            const __bf16* sr = &sm[row * OST + hp * 256];
            bf16x4 gl = *(const bf16x4*)&sr[c0];
            bf16x4 cl = *(const bf16x4*)&sr[128 + c0];
            unsigned int wds[4];
            #pragma unroll
            for (int i = 0; i < 4; ++i) {
                bf16x2 pr = { gl[i], cl[i] };
                wds[i] = __builtin_bit_cast(unsigned int, pr);
            }
            unsigned int* dp = hp ? pbI : paI;
            *(uint4*)&dp[(size_t)node * 128 + c0] = *(const uint4*)&wds[0];
        }
    }
}

// ---- edge kernel: coalesced pre-gathered header + staged-LDS packed sums
// (16B loads) + tiny ef-MFMA with bias in the C operand + IN-PLACE f32
// activation + R7-PROVEN run-segmented reduction (one atomic per run).
// R9 lesson: the 4-edge in-register windowed reduce caused same-address
// intra-wave atomic serialization (WRITE_SIZE 48->175MB, 3x slower). The
// 16-edge serial loop IS the aggregation -- keep it. ----
__global__ __launch_bounds__(512, 6) void edge_fuse(
    const unsigned int* __restrict__ paI, const unsigned int* __restrict__ pbI,
    const unsigned int* __restrict__ sdx, const unsigned short* __restrict__ eidlo,
    const unsigned char* __restrict__ eidhi,
    const float* __restrict__ ef, const __bf16* __restrict__ wef,
    const float* __restrict__ gb, const float* __restrict__ cb,
    float* __restrict__ agg)
{
    __shared__ __align__(16) unsigned int sbuf[TE * SST];  // 33,792 B sums -> m
    __shared__ __align__(16) __bf16 zE[TE * 32];           // 4 KB
    __shared__ int s_src[TE], s_dst[TE];

    const int t  = threadIdx.x;
    const int e0 = blockIdx.x * TE;
    const int w = t >> 6, l = t & 63, quad = l >> 4, col16 = l & 15;

    // early independent loads (in flight across the header)
    const __bf16* wpp = &wef[(size_t)((w * 2) * 64 + l) * 8];
    bf16x8 bfr0 = *(const bf16x8*)&wpp[0];
    bf16x8 bfr1 = *(const bf16x8*)&wpp[512];
    const int c = w * 16 + col16;
    const float gbv = gb[c], cbv = cb[c];

    if (t < TE) {
        unsigned int sd = sdx[e0 + t];     // coalesced 4B
        int eid = (int)eidlo[e0 + t] | ((int)eidhi[e0 + t] << 16);
        s_src[t] = (int)(sd & 0xFFFFu);
        s_dst[t] = (int)(sd >> 16);
        // ef row -> zE (k 0..9 live, 10..31 zero)
        const float* efr = &ef[(size_t)eid * DE];
        __bf16* row = &zE[t * 32];
        #pragma unroll
        for (int j = 0; j < 5; ++j) {
            float2 a = *(const float2*)&efr[j * 2];
            bf16x2 pr = { (__bf16)a.x, (__bf16)a.y };
            *(bf16x2*)&row[j * 2] = pr;
        }
        *(bf16x2*)&row[10] = (bf16x2)(__bf16)0.0f;
        *(bf16x4*)&row[12] = (bf16x4)(__bf16)0.0f;
        *(bf16x8*)&row[16] = (bf16x8)(__bf16)0.0f;
        *(bf16x8*)&row[24] = (bf16x8)(__bf16)0.0f;
    }
    __syncthreads();

    // staged packed sums: 1024 tasks = 64 edges x 16 col-groups of 8.
    // 16B loads from interleaved proj (512B contiguous per edge -> coalesced).
    #pragma unroll
    for (int it = 0; it < 2; ++it) {
        int id  = it * 512 + t;
        int e   = id >> 4, grp = id & 15;
        int src = s_src[e], dst = s_dst[e];
        int c0  = grp * 8;
        u32x4 a0 = *(const u32x4*)&paI[(size_t)src * 128 + c0];
        u32x4 a1 = *(const u32x4*)&paI[(size_t)src * 128 + c0 + 4];
        u32x4 b0 = *(const u32x4*)&pbI[(size_t)dst * 128 + c0];
        u32x4 b1 = *(const u32x4*)&pbI[(size_t)dst * 128 + c0 + 4];
        unsigned int o[8];
        #pragma unroll
        for (int j = 0; j < 4; ++j) {
            bf16x2 p0 = { (__bf16)(bflo(a0[j]) + bflo(b0[j])),
                          (__bf16)(bfhi(a0[j]) + bfhi(b0[j])) };
            bf16x2 p1 = { (__bf16)(bflo(a1[j]) + bflo(b1[j])),
                          (__bf16)(bfhi(a1[j]) + bfhi(b1[j])) };
            o[j]     = __builtin_bit_cast(unsigned int, p0);
            o[j + 4] = __builtin_bit_cast(unsigned int, p1);
        }
        *(uint4*)&sbuf[e * SST + c0]     = *(const uint4*)&o[0];
        *(uint4*)&sbuf[e * SST + c0 + 4] = *(const uint4*)&o[4];
    }
    __syncthreads();

    // ef @ W_ef with bias as the MFMA C operand (saves the adds later)
    const f32x4 bg4 = { gbv, gbv, gbv, gbv };
    const f32x4 bc4 = { cbv, cbv, cbv, cbv };
    f32x4 accg[4], accc[4];
    #pragma unroll
    for (int mt = 0; mt < 4; ++mt) {
        const bf16x8 a = *(const bf16x8*)&zE[(mt * 16 + col16) * 32 + quad * 8];
        accg[mt] = __builtin_amdgcn_mfma_f32_16x16x32_bf16(a, bfr0, bg4, 0, 0, 0);
        accc[mt] = __builtin_amdgcn_mfma_f32_16x16x32_bf16(a, bfr1, bc4, 0, 0, 0);
    }

    // activation in-place: packed sum word -> f32 m (owner-exclusive slot)
    #pragma unroll
    for (int mt = 0; mt < 4; ++mt) {
        #pragma unroll
        for (int r = 0; r < 4; ++r) {
            int e = mt * 16 + quad * 4 + r;
            unsigned int u = sbuf[e * SST + c];
            float g = bflo(u) + accg[mt][r];
            float x = bfhi(u) + accc[mt][r];
            ((float*)sbuf)[e * SST + c] = fast_sigmoid(g) * fast_softplus(x);
        }
    }
    __syncthreads();

    // run-segmented reduction, one atomic per run; 4 segs x 128 cols
    const int seg = t >> 7;
    const int cc  = t & 127;
    const int rlo = seg * 16, rhi = rlo + 16;
    int   cur = s_src[rlo];
    float s   = 0.0f;
    const float* ms = (const float*)sbuf;
    for (int e = rlo; e < rhi; ++e) {
        int node = s_src[e];
        float v  = ms[e * SST + cc];
        if (node != cur) {
            atomicAdd(&agg[(size_t)cur * D + cc], s);
            s = 0.0f; cur = node;
        }
        s += v;
    }
    atomicAdd(&agg[(size_t)cur * D + cc], s);
}

__global__ __launch_bounds__(256) void col_stats(
    const float* __restrict__ agg, float* __restrict__ stats)
{
    const int t    = threadIdx.x;
    const int col  = t & 127;
    const int half = t >> 7;
    float s = 0.0f, s2 = 0.0f;
    for (int r = blockIdx.x * 2 + half; r < N_NODES; r += gridDim.x * 2) {
        float v = agg[(size_t)r * D + col];
        s += v; s2 += v * v;
    }
    atomicAdd(&stats[col], s);
    atomicAdd(&stats[128 + col], s2);
}

__global__ __launch_bounds__(256) void out_softplus(
    const float* __restrict__ h, const float* __restrict__ agg,
    const float* __restrict__ stats, const float* __restrict__ gamma,
    const float* __restrict__ beta, float* __restrict__ out)
{
    __shared__ float sc[128], bi[128];
    int t = threadIdx.x;
    if (t < 128) {
        const float inv_n = 1.0f / (float)N_NODES;
        float mean = stats[t] * inv_n;
        float var  = stats[128 + t] * inv_n - mean * mean;
        var = fmaxf(var, 0.0f);
        float rstd = rsqrtf(var + 1e-5f);
        float s = rstd * gamma[t];
        sc[t] = s;
        bi[t] = beta[t] - mean * s;
    }
    __syncthreads();
    int idx4 = blockIdx.x * 256 + t;
    int base = idx4 * 4;
    if (base < N_NODES * D) {
        float4 hv = *(const float4*)&h[base];
        float4 av = *(const float4*)&agg[base];
        int c = base & 127;
        float4 o;
        o.x = fast_softplus(hv.x + av.x * sc[c + 0] + bi[c + 0]);
        o.y = fast_softplus(hv.y + av.y * sc[c + 1] + bi[c + 1]);
        o.z = fast_softplus(hv.z + av.z * sc[c + 2] + bi[c + 2]);
        o.w = fast_softplus(hv.w + av.w * sc[c + 3] + bi[c + 3]);
        *(float4*)&out[base] = o;
    }
}

extern "C" void kernel_launch(void* const* d_in, const int* in_sizes, int n_in,
                              void* d_out, int out_size, void* d_ws, size_t ws_size,
                              hipStream_t stream) {
    const float* h     = (const float*)d_in[0];
    const int*   ei    = (const int*)  d_in[1];
    const float* ef    = (const float*)d_in[2];
    const float* gw    = (const float*)d_in[3];
    const float* gb    = (const float*)d_in[4];
    const float* cw    = (const float*)d_in[5];
    const float* cb    = (const float*)d_in[6];
    const float* gamma = (const float*)d_in[7];
    const float* beta  = (const float*)d_in[8];
    float* out = (float*)d_out;

    // Layout: [agg 25.6M][stats 1K][U: counts 3.2M -> pbI 25.6M][wp2 128K]
    //         [wef 16K][bsum 1K][anchors 1K][excl16 100K][rank 800K]
    //         [sdx 3.2M][eidlo 1.6M][eidhi 800K]  ~= 57.85 MB (< 58.6 proven)
    float*          agg     = (float*)d_ws;
    float*          stats   = agg + (size_t)N_NODES * D;
    int*            counts  = (int*)(stats + 256);           // U base (strided hist)
    unsigned int*   pbI     = (unsigned int*)counts;         // aliases U after scan_final
    char*           afterU  = (char*)counts + (size_t)N_NODES * 128 * sizeof(unsigned int);
    __bf16*         wp2     = (__bf16*)afterU;               // 131,072 B
    __bf16*         wef     = wp2 + WP2_ELEMS;               // 16,384 B
    int*            bsum    = (int*)(wef + WEF_ELEMS);       // 1 KB
    int*            anchors = bsum + 256;                    // 1 KB (196 used)
    unsigned short* excl16  = (unsigned short*)(anchors + 256);   // 100 KB
    unsigned char*  rank    = (unsigned char*)(excl16 + N_NODES); // 800 KB
    unsigned int*   sdx     = (unsigned int*)(rank + N_EDGES);    // 3.2 MB (4B-aligned)
    unsigned short* eidlo   = (unsigned short*)(sdx + N_EDGES);   // 1.6 MB
    unsigned char*  eidhi   = (unsigned char*)(eidlo + N_EDGES);  // 800 KB
    unsigned int*   paI     = (unsigned int*)d_out;          // 25.6 MB scratch until out

    // zero agg | stats | counts (one contiguous region)
    const size_t zero_bytes = ((size_t)N_NODES * D + 256) * sizeof(float)
                            + (size_t)N_NODES * CSTRIDE * sizeof(int);
    hipMemsetAsync(d_ws, 0, zero_bytes, stream);
    prep<<<3413, 256, 0, stream>>>(gw, cw, ei, wp2, wef, counts, rank);
    scan_partials<<<SCAN_BLOCKS, 256, 0, stream>>>(counts, bsum);
    scan_final<<<SCAN_BLOCKS, 256, 0, stream>>>(counts, bsum, anchors, excl16);
    scatter_gemm<<<SCAT_BLOCKS + GEMM_BLOCKS, 512, 0, stream>>>(
        ei, rank, anchors, excl16, sdx, eidlo, eidhi, h, wp2, paI, pbI);
    edge_fuse<<<N_TILES, 512, 0, stream>>>(
        paI, pbI, sdx, eidlo, eidhi, ef, wef, gb, cb, agg);
    col_stats<<<784, 256, 0, stream>>>(agg, stats);
    out_softplus<<<N_NODES * D / 4 / 256, 256, 0, stream>>>(
        h, agg, stats, gamma, beta, out);
}